// Round 2
// baseline (319.406 us; speedup 1.0000x reference)
//
#include <hip/hip_runtime.h>
#include <stdint.h>

typedef unsigned short u16;
typedef __bf16  bf16x8   __attribute__((ext_vector_type(8)));
typedef float   floatx4  __attribute__((ext_vector_type(4)));
typedef unsigned short ushortx4 __attribute__((ext_vector_type(4)));

__device__ __forceinline__ u16 f2bf(float f) {
  unsigned u = __builtin_bit_cast(unsigned, f);
  u += 0x7FFFu + ((u >> 16) & 1u);           // RNE; inputs are finite
  return (u16)(u >> 16);
}

#define GLD_LDS16(g, l)                                                        \
  __builtin_amdgcn_global_load_lds(                                            \
      (const __attribute__((address_space(1))) void*)(g),                      \
      (__attribute__((address_space(3))) void*)(l), 16, 0, 0)

// ---------------------------------------------------------------------------
// Kernel 0a: weights fp32 -> bf16 (unchanged; verified).
// ---------------------------------------------------------------------------
__global__ __launch_bounds__(256) void cvt_w(
    const float* __restrict__ Wq, const float* __restrict__ Wk,
    const float* __restrict__ Wv, u16* __restrict__ dst)
{
  const int z = blockIdx.y;
  const float* src = (z == 0) ? Wq : (z == 1) ? Wk : Wv;
  u16* d = dst + (size_t)z * 262144;
  const int idx = (blockIdx.x * 256 + threadIdx.x) * 8;
  const float4 lo = *(const float4*)&src[idx];
  const float4 hi = *(const float4*)&src[idx + 4];
  union { u16 h[8]; uint4 v; } pk;
  pk.h[0] = f2bf(lo.x); pk.h[1] = f2bf(lo.y); pk.h[2] = f2bf(lo.z); pk.h[3] = f2bf(lo.w);
  pk.h[4] = f2bf(hi.x); pk.h[5] = f2bf(hi.y); pk.h[6] = f2bf(hi.z); pk.h[7] = f2bf(hi.w);
  *(uint4*)&d[idx] = pk.v;
}

// ---------------------------------------------------------------------------
// Kernel 0b: x fp32 -> bf16 (unchanged; verified).
// ---------------------------------------------------------------------------
__global__ __launch_bounds__(256) void cvt_x(
    const float* __restrict__ X, u16* __restrict__ dst)
{
  const int idx = (blockIdx.x * 256 + threadIdx.x) * 8;
  const float4 lo = *(const float4*)&X[idx];
  const float4 hi = *(const float4*)&X[idx + 4];
  union { u16 h[8]; uint4 v; } pk;
  pk.h[0] = f2bf(lo.x); pk.h[1] = f2bf(lo.y); pk.h[2] = f2bf(lo.z); pk.h[3] = f2bf(lo.w);
  pk.h[4] = f2bf(hi.x); pk.h[5] = f2bf(hi.y); pk.h[6] = f2bf(hi.z); pk.h[7] = f2bf(hi.w);
  *(uint4*)&dst[idx] = pk.v;
}

// ---------------------------------------------------------------------------
// Kernel 1: fused QKV projection — m97 core (verified), unchanged.
// ---------------------------------------------------------------------------
__global__ __launch_bounds__(256, 2) void qkv_gemm(
    const u16* __restrict__ X16, const u16* __restrict__ Wb,
    u16* __restrict__ qo, u16* __restrict__ ko, u16* __restrict__ vto)
{
  __shared__ u16 As[128 * 32];
  __shared__ u16 Bs[128 * 32];

  const int tid = threadIdx.x;
  const int w  = tid >> 6, l = tid & 63;
  const int lr = l & 15, lq = l >> 4;
  const int lk = lq * 8;
  const int m0 = blockIdx.x * 128;
  const int n0 = blockIdx.y * 128;
  const int z  = blockIdx.z;
  const u16* W = Wb + (size_t)z * 262144;
  const int wm = (w & 1) * 64, wn = (w >> 1) * 64;

  floatx4 acc[4][4];
  const floatx4 fz = {0.f, 0.f, 0.f, 0.f};
#pragma unroll
  for (int i = 0; i < 4; ++i)
#pragma unroll
    for (int j = 0; j < 4; ++j) acc[i][j] = fz;

  for (int kk = 0; kk < 512; kk += 32) {
    __syncthreads();
#pragma unroll
    for (int i = 0; i < 2; ++i) {
      const int c = i * 256 + tid;
      const int row = c >> 2, c8 = (c & 3) * 8;
      GLD_LDS16(X16 + (size_t)(m0 + row) * 512 + kk + c8, &As[c * 8]);
      GLD_LDS16(W   + (size_t)(n0 + row) * 512 + kk + c8, &Bs[c * 8]);
    }
    __syncthreads();

    bf16x8 af[4], bfr[4];
#pragma unroll
    for (int t = 0; t < 4; ++t) {
      af[t]  = *(const bf16x8*)&As[(wm + t * 16 + lr) * 32 + lk];
      bfr[t] = *(const bf16x8*)&Bs[(wn + t * 16 + lr) * 32 + lk];
    }
#pragma unroll
    for (int i = 0; i < 4; ++i)
#pragma unroll
      for (int j = 0; j < 4; ++j)
        acc[i][j] = __builtin_amdgcn_mfma_f32_16x16x32_bf16(af[i], bfr[j],
                                                            acc[i][j], 0, 0, 0);
  }

  const int cr = lq * 4;   // C layout: col=lane&15, row=quad*4+reg
  if (z == 2) {
#pragma unroll
    for (int i = 0; i < 4; ++i)
#pragma unroll
      for (int j = 0; j < 4; ++j) {
        const int n = n0 + wn + j * 16 + lr;           // d
        const int m = m0 + wm + i * 16 + cr;           // key (b*4096+s)
        ushortx4 pk;
#pragma unroll
        for (int r = 0; r < 4; ++r) pk[r] = f2bf(acc[i][j][r]);
        *(ushortx4*)&vto[(size_t)n * 16384 + m] = pk;  // vt[d][b*S+s]
      }
  } else {
    u16* dst = (z == 0) ? qo : ko;
    const float sc = (z == 0) ? 0.06375871732f : 1.0f; // log2(e)/sqrt(512)
#pragma unroll
    for (int i = 0; i < 4; ++i)
#pragma unroll
      for (int j = 0; j < 4; ++j) {
        const int m = m0 + wm + i * 16 + cr;
        const int n = n0 + wn + j * 16 + lr;
#pragma unroll
        for (int r = 0; r < 4; ++r)
          dst[(size_t)(m + r) * 512 + n] = f2bf(acc[i][j][r] * sc);
      }
  }
}

// ---------------------------------------------------------------------------
// Kernel 2 (REWRITTEN this round): 8-phase 256^2 schedule (m201 template).
// A = k (M = 256 keys), B = q (N = 256 q-rows), BK = 64, 512 thr = 8 waves.
//
// Wave->fragment mapping (interleaved so quadrants = LDS halves for EVERY
// wave): A row(in-tile) = fm*32 + (w&1)*16 + lr, fm in 0..7;
//        B row(in-tile) = fn*64 + (w>>1)*16 + lr, fn in 0..3.
// Quadrant qd = (fmh=qd>>1, fnh=qd&1): reads A-half fmh, B-half fnh only.
//
// LDS: 2 K-tile buffers x (A 256x64 + B 256x64) bf16 = 128 KiB.
// Swizzle (both-sides, rule #21): physical (row, k16) holds logical
// (row, k16 ^ (row&7)); staging pre-swizzles the GLOBAL source chunk,
// ds_read applies the same XOR -> ds_read_b128 ~2-way conflicts (free).
//
// Stage stream s: [A0,B0,A1,B1] per K-tile ts=s>>2, staged at phase s-6
// (6 half-tiles in flight).  Slot-free proof: A0 last read at q1, B0 at q2,
// A1/B1 at q3 -> stage phases 4t+2/4t+3/4t+4/4t+5 for tile t+2 all follow
// the last-reader's barrier#2.  Readiness: vmcnt(4) at end of each q3
// drains all but the 2 newest half-tiles => the ENTIRE next K-tile is
// resident before its first quadrant.  Tail peel: t=6 ends with vmcnt(0)
// (stream exhausted, the counted form would under-wait); t=7 stages nothing.
// ---------------------------------------------------------------------------
__global__ __launch_bounds__(512, 2) void qk_exp8(
    const u16* __restrict__ q, const u16* __restrict__ k,
    u16* __restrict__ S, float* __restrict__ lsum)
{
  __shared__ u16 lds[65536];                   // 128 KiB

  const int tid = threadIdx.x;
  const int w  = tid >> 6, l = tid & 63;
  const int lr = l & 15, lq = l >> 4;
  const int wA = (w & 1) * 16;                 // A (key) strip
  const int wB = (w >> 1) * 16;                // B (qrow) strip
  const int kb0 = blockIdx.x * 256;            // key base
  const int qb0 = blockIdx.y * 256;            // qrow base
  const int b   = blockIdx.z;
  const size_t rb = (size_t)b * 4096;
  const u16* kg = k + rb * 512;
  const u16* qg = q + rb * 512;

  floatx4 acc[8][4];
  const floatx4 fz = {0.f, 0.f, 0.f, 0.f};
#pragma unroll
  for (int i = 0; i < 8; ++i)
#pragma unroll
    for (int j = 0; j < 4; ++j) acc[i][j] = fz;

  // stage half-tile s of the stream (s compile-time after unroll)
  auto stage = [&](int s) {
    const int ts = s >> 2, kind = s & 3;
    const int mat = kind & 1, h = kind >> 1;   // mat: 0=A(k) 1=B(q)
    const u16* src = mat ? qg : kg;
    const int rbase = mat ? qb0 : kb0;
    u16* dst = &lds[(ts & 1) * 32768 + mat * 16384];
#pragma unroll
    for (int i = 0; i < 2; ++i) {
      const int c = i * 512 + tid;             // 16B chunk within half
      const int r = h * 128 + (c >> 3), k16 = c & 7;
      const int k16s = k16 ^ (r & 7);          // inverse-swizzled source
      GLD_LDS16(src + (size_t)(rbase + r) * 512 + ts * 64 + k16s * 8,
                &dst[r * 64 + k16 * 8]);
    }
  };

  // prologue: 6 half-tiles (tile0 complete + A0,B0 of tile1)
#pragma unroll
  for (int s = 0; s < 6; ++s) stage(s);
  asm volatile("s_waitcnt vmcnt(4)" ::: "memory");   // tile0 resident
  __builtin_amdgcn_s_barrier();
  __builtin_amdgcn_sched_barrier(0);

#pragma unroll
  for (int t = 0; t < 8; ++t) {
#pragma unroll
    for (int qd = 0; qd < 4; ++qd) {
      const int fmh = qd >> 1, fnh = qd & 1;
      const u16* AB = &lds[(t & 1) * 32768];
      const u16* BB = AB + 16384;

      // ---- ds-reads for this quadrant (12 x ds_read_b128) ----
      bf16x8 af[4][2], bfv[2][2];
#pragma unroll
      for (int im = 0; im < 4; ++im) {
        const int rA = (fmh * 4 + im) * 32 + wA + lr;
#pragma unroll
        for (int ks = 0; ks < 2; ++ks) {
          const int k16p = (ks * 4 + lq) ^ (rA & 7);
          af[im][ks] = *(const bf16x8*)&AB[rA * 64 + k16p * 8];
        }
      }
#pragma unroll
      for (int jn = 0; jn < 2; ++jn) {
        const int rB = (fnh * 2 + jn) * 64 + wB + lr;
#pragma unroll
        for (int ks = 0; ks < 2; ++ks) {
          const int k16p = (ks * 4 + lq) ^ (rB & 7);
          bfv[jn][ks] = *(const bf16x8*)&BB[rB * 64 + k16p * 8];
        }
      }

      // ---- stage one half-tile (2 x global_load_lds) ----
      const int s = t * 4 + qd + 6;
      if (s < 32) stage(s);

      __builtin_amdgcn_sched_barrier(0);
      __builtin_amdgcn_s_barrier();
      asm volatile("s_waitcnt lgkmcnt(0)" ::: "memory");
      __builtin_amdgcn_sched_barrier(0);        // rule #18: pin MFMA after wait

      __builtin_amdgcn_s_setprio(1);
#pragma unroll
      for (int im = 0; im < 4; ++im)
#pragma unroll
        for (int jn = 0; jn < 2; ++jn)
#pragma unroll
          for (int ks = 0; ks < 2; ++ks)
            acc[fmh * 4 + im][fnh * 2 + jn] =
                __builtin_amdgcn_mfma_f32_16x16x32_bf16(
                    af[im][ks], bfv[jn][ks],
                    acc[fmh * 4 + im][fnh * 2 + jn], 0, 0, 0);
      __builtin_amdgcn_s_setprio(0);

      if (qd == 3) {
        if (t < 6)        asm volatile("s_waitcnt vmcnt(4)" ::: "memory");
        else if (t == 6)  asm volatile("s_waitcnt vmcnt(0)" ::: "memory");
      }
      __builtin_amdgcn_s_barrier();
      __builtin_amdgcn_sched_barrier(0);
    }
  }

  // ---- epilogue: exp2, packed 8B P stores, per-qrow sum atomics ----
  // acc[fm][fn]: key = kb0 + fm*32 + wA + lq*4 + r (4 consecutive keys),
  //              qrow = qb0 + fn*64 + wB + lr.
  const int cr = lq * 4;
  u16* Sb = S + ((size_t)b << 24);             // b * 4096 * 4096
  float js[4] = {0.f, 0.f, 0.f, 0.f};
#pragma unroll
  for (int fm = 0; fm < 8; ++fm)
#pragma unroll
    for (int fn = 0; fn < 4; ++fn) {
      const int key = kb0 + fm * 32 + wA + cr;
      const int qr  = qb0 + fn * 64 + wB + lr;
      ushortx4 pk;
      float s4 = 0.f;
#pragma unroll
      for (int r = 0; r < 4; ++r) {
        const float p = __builtin_amdgcn_exp2f(acc[fm][fn][r] - 17.31234049f);
        s4 += p;
        pk[r] = f2bf(p);
      }
      js[fn] += s4;
      *(ushortx4*)&Sb[(size_t)qr * 4096 + key] = pk;
    }
#pragma unroll
  for (int fn = 0; fn < 4; ++fn) {
    float s = js[fn];
    s += __shfl_xor(s, 16);                    // reduce over key-quads (lq)
    s += __shfl_xor(s, 32);
    if (lq == 0)
      atomicAdd(&lsum[rb + qb0 + fn * 64 + wB + lr], s);
  }
}

// ---------------------------------------------------------------------------
// Kernel 3: O = (P V) / lsum  (m97 core + XCD-chunked swizzle; unchanged —
// round-1 control, ~92 us).
// ---------------------------------------------------------------------------
__global__ __launch_bounds__(256, 2) void pv(
    const u16* __restrict__ S, const u16* __restrict__ vt,
    const float* __restrict__ lsum, float* __restrict__ out)
{
  __shared__ u16 As[128 * 32];
  __shared__ u16 Bs[128 * 32];

  const int tid = threadIdx.x;
  const int w  = tid >> 6, l = tid & 63;
  const int lr = l & 15, lq = l >> 4;
  const int lk = lq * 8;

  const int wg = blockIdx.x;                     // 0..511
  const int li = (wg & 7) * 64 + (wg >> 3);      // logical index, bijective
  const int n0 = (li & 3) * 128;                 // d
  const int m0 = ((li >> 2) & 31) * 128;         // q row within batch
  const int b  = li >> 7;
  const int wm = (w & 1) * 64, wn = (w >> 1) * 64;
  const u16* Sb = S + ((size_t)b << 24);

  floatx4 acc[4][4];
  const floatx4 fz = {0.f, 0.f, 0.f, 0.f};
#pragma unroll
  for (int i = 0; i < 4; ++i)
#pragma unroll
    for (int j = 0; j < 4; ++j) acc[i][j] = fz;

  for (int kk = 0; kk < 4096; kk += 32) {
    __syncthreads();
#pragma unroll
    for (int i = 0; i < 2; ++i) {
      const int c = i * 256 + tid;
      const int row = c >> 2, c8 = (c & 3) * 8;
      GLD_LDS16(Sb + (size_t)(m0 + row) * 4096 + kk + c8, &As[c * 8]);
      GLD_LDS16(vt + (size_t)(n0 + row) * 16384 + b * 4096 + kk + c8, &Bs[c * 8]);
    }
    __syncthreads();

    bf16x8 af[4], bfr[4];
#pragma unroll
    for (int t = 0; t < 4; ++t) {
      af[t]  = *(const bf16x8*)&As[(wm + t * 16 + lr) * 32 + lk];
      bfr[t] = *(const bf16x8*)&Bs[(wn + t * 16 + lr) * 32 + lk];
    }
#pragma unroll
    for (int i = 0; i < 4; ++i)
#pragma unroll
      for (int j = 0; j < 4; ++j)
        acc[i][j] = __builtin_amdgcn_mfma_f32_16x16x32_bf16(af[i], bfr[j],
                                                            acc[i][j], 0, 0, 0);
  }

  const int cr = lq * 4;
#pragma unroll
  for (int i = 0; i < 4; ++i) {
    const int m = m0 + wm + i * 16 + cr;
    float inv[4];
#pragma unroll
    for (int r = 0; r < 4; ++r)
      inv[r] = 1.0f / lsum[(size_t)b * 4096 + m + r];
#pragma unroll
    for (int j = 0; j < 4; ++j) {
      const int n = n0 + wn + j * 16 + lr;
#pragma unroll
      for (int r = 0; r < 4; ++r)
        out[((size_t)b * 4096 + m + r) * 512 + n] = acc[i][j][r] * inv[r];
    }
  }
}

// ---------------------------------------------------------------------------
extern "C" void kernel_launch(void* const* d_in, const int* in_sizes, int n_in,
                              void* d_out, int out_size, void* d_ws, size_t ws_size,
                              hipStream_t stream) {
  (void)in_sizes; (void)n_in; (void)out_size; (void)ws_size;
  const float* x  = (const float*)d_in[0];
  const float* Wq = (const float*)d_in[1];
  const float* Wk = (const float*)d_in[2];
  const float* Wv = (const float*)d_in[3];
  float* out = (float*)d_out;
  u16* ws  = (u16*)d_ws;
  u16* qw  = ws;                                  // q row-major, 16 MB
  u16* kw  = qw + (size_t)16384 * 512;            // k row-major, 16 MB
  u16* vw  = kw + (size_t)16384 * 512;            // v^T [512][16384], 16 MB
  u16* x16 = vw + (size_t)16384 * 512;            // x bf16, 16 MB
  u16* wb  = x16 + (size_t)16384 * 512;           // weights bf16, 1.5 MB
  u16* Sp  = wb + (size_t)3 * 262144;             // P bf16 [4][4096][4096], 128 MB
  float* lsum = (float*)(Sp + ((size_t)4 << 24)); // [16384] fp32, 64 KB

  hipMemsetAsync(lsum, 0, 16384 * sizeof(float), stream);
  cvt_w<<<dim3(128, 3), dim3(256), 0, stream>>>(Wq, Wk, Wv, wb);
  cvt_x<<<dim3(4096), dim3(256), 0, stream>>>(x, x16);
  qkv_gemm<<<dim3(128, 4, 3), dim3(256), 0, stream>>>(x16, wb, qw, kw, vw);
  qk_exp8<<<dim3(16, 16, 4), dim3(512), 0, stream>>>(qw, kw, Sp, lsum);
  pv<<<dim3(512), dim3(256), 0, stream>>>(Sp, vw, lsum, out);
}

// Round 3
// 290.953 us; speedup vs baseline: 1.0978x; 1.0978x over previous
//
#include <hip/hip_runtime.h>
#include <stdint.h>

typedef unsigned short u16;
typedef __bf16  bf16x8   __attribute__((ext_vector_type(8)));
typedef float   floatx4  __attribute__((ext_vector_type(4)));
typedef unsigned short ushortx4 __attribute__((ext_vector_type(4)));

__device__ __forceinline__ u16 f2bf(float f) {
  unsigned u = __builtin_bit_cast(unsigned, f);
  u += 0x7FFFu + ((u >> 16) & 1u);           // RNE; inputs are finite
  return (u16)(u >> 16);
}

#define GLD_LDS16(g, l)                                                        \
  __builtin_amdgcn_global_load_lds(                                            \
      (const __attribute__((address_space(1))) void*)(g),                      \
      (__attribute__((address_space(3))) void*)(l), 16, 0, 0)

#define VMW(N) asm volatile("s_waitcnt vmcnt(" #N ")" ::: "memory")

// ---------------------------------------------------------------------------
// Kernel 0a: weights fp32 -> bf16 (unchanged; verified).
// ---------------------------------------------------------------------------
__global__ __launch_bounds__(256) void cvt_w(
    const float* __restrict__ Wq, const float* __restrict__ Wk,
    const float* __restrict__ Wv, u16* __restrict__ dst)
{
  const int z = blockIdx.y;
  const float* src = (z == 0) ? Wq : (z == 1) ? Wk : Wv;
  u16* d = dst + (size_t)z * 262144;
  const int idx = (blockIdx.x * 256 + threadIdx.x) * 8;
  const float4 lo = *(const float4*)&src[idx];
  const float4 hi = *(const float4*)&src[idx + 4];
  union { u16 h[8]; uint4 v; } pk;
  pk.h[0] = f2bf(lo.x); pk.h[1] = f2bf(lo.y); pk.h[2] = f2bf(lo.z); pk.h[3] = f2bf(lo.w);
  pk.h[4] = f2bf(hi.x); pk.h[5] = f2bf(hi.y); pk.h[6] = f2bf(hi.z); pk.h[7] = f2bf(hi.w);
  *(uint4*)&d[idx] = pk.v;
}

// ---------------------------------------------------------------------------
// Kernel 0b: x fp32 -> bf16 (unchanged; verified).
// ---------------------------------------------------------------------------
__global__ __launch_bounds__(256) void cvt_x(
    const float* __restrict__ X, u16* __restrict__ dst)
{
  const int idx = (blockIdx.x * 256 + threadIdx.x) * 8;
  const float4 lo = *(const float4*)&X[idx];
  const float4 hi = *(const float4*)&X[idx + 4];
  union { u16 h[8]; uint4 v; } pk;
  pk.h[0] = f2bf(lo.x); pk.h[1] = f2bf(lo.y); pk.h[2] = f2bf(lo.z); pk.h[3] = f2bf(lo.w);
  pk.h[4] = f2bf(hi.x); pk.h[5] = f2bf(hi.y); pk.h[6] = f2bf(hi.z); pk.h[7] = f2bf(hi.w);
  *(uint4*)&dst[idx] = pk.v;
}

// ---------------------------------------------------------------------------
// Kernel 1: fused QKV projection — m97 core (verified), unchanged.
// ---------------------------------------------------------------------------
__global__ __launch_bounds__(256, 2) void qkv_gemm(
    const u16* __restrict__ X16, const u16* __restrict__ Wb,
    u16* __restrict__ qo, u16* __restrict__ ko, u16* __restrict__ vto)
{
  __shared__ u16 As[128 * 32];
  __shared__ u16 Bs[128 * 32];

  const int tid = threadIdx.x;
  const int w  = tid >> 6, l = tid & 63;
  const int lr = l & 15, lq = l >> 4;
  const int lk = lq * 8;
  const int m0 = blockIdx.x * 128;
  const int n0 = blockIdx.y * 128;
  const int z  = blockIdx.z;
  const u16* W = Wb + (size_t)z * 262144;
  const int wm = (w & 1) * 64, wn = (w >> 1) * 64;

  floatx4 acc[4][4];
  const floatx4 fz = {0.f, 0.f, 0.f, 0.f};
#pragma unroll
  for (int i = 0; i < 4; ++i)
#pragma unroll
    for (int j = 0; j < 4; ++j) acc[i][j] = fz;

  for (int kk = 0; kk < 512; kk += 32) {
    __syncthreads();
#pragma unroll
    for (int i = 0; i < 2; ++i) {
      const int c = i * 256 + tid;
      const int row = c >> 2, c8 = (c & 3) * 8;
      GLD_LDS16(X16 + (size_t)(m0 + row) * 512 + kk + c8, &As[c * 8]);
      GLD_LDS16(W   + (size_t)(n0 + row) * 512 + kk + c8, &Bs[c * 8]);
    }
    __syncthreads();

    bf16x8 af[4], bfr[4];
#pragma unroll
    for (int t = 0; t < 4; ++t) {
      af[t]  = *(const bf16x8*)&As[(wm + t * 16 + lr) * 32 + lk];
      bfr[t] = *(const bf16x8*)&Bs[(wn + t * 16 + lr) * 32 + lk];
    }
#pragma unroll
    for (int i = 0; i < 4; ++i)
#pragma unroll
      for (int j = 0; j < 4; ++j)
        acc[i][j] = __builtin_amdgcn_mfma_f32_16x16x32_bf16(af[i], bfr[j],
                                                            acc[i][j], 0, 0, 0);
  }

  const int cr = lq * 4;   // C layout: col=lane&15, row=quad*4+reg
  if (z == 2) {
#pragma unroll
    for (int i = 0; i < 4; ++i)
#pragma unroll
      for (int j = 0; j < 4; ++j) {
        const int n = n0 + wn + j * 16 + lr;           // d
        const int m = m0 + wm + i * 16 + cr;           // key (b*4096+s)
        ushortx4 pk;
#pragma unroll
        for (int r = 0; r < 4; ++r) pk[r] = f2bf(acc[i][j][r]);
        *(ushortx4*)&vto[(size_t)n * 16384 + m] = pk;  // vt[d][b*S+s]
      }
  } else {
    u16* dst = (z == 0) ? qo : ko;
    const float sc = (z == 0) ? 0.06375871732f : 1.0f; // log2(e)/sqrt(512)
#pragma unroll
    for (int i = 0; i < 4; ++i)
#pragma unroll
      for (int j = 0; j < 4; ++j) {
        const int m = m0 + wm + i * 16 + cr;
        const int n = n0 + wn + j * 16 + lr;
#pragma unroll
        for (int r = 0; r < 4; ++r)
          dst[(size_t)(m + r) * 512 + n] = f2bf(acc[i][j][r] * sc);
      }
  }
}

// ---------------------------------------------------------------------------
// Kernel 2: 8-phase 256^2 (m201 template), A=k (M=keys), B=q (N=qrows).
// CHANGED (this round): Gray-code quadrant order (0,0)->(0,1)->(1,1)->(1,0)
// with persistent operand registers: A-half read once per half (q0,q2),
// B-halves read once each (q0,q1) into bf0/bf1 that live across barriers.
// ds_read_b128 per K-tile per wave: 48 -> 24 (the template's minimum);
// phase read pattern 12/4/8/0.  Stage stream + vmcnt schedule UNCHANGED
// from the verified round-2 kernel.  Race-check (1 barrier + lgkmcnt(0)
// suffices: all waves' reads drain before anyone passes the phase's 2nd
// barrier): A-h0 read q0 / staged(t+2) q2 OK; B-h0 read q0 / staged q3 OK;
// A1,B1(t+1) stage at q0,q1 target the OPPOSITE buffer.  Numerics identical
// (same acc buckets, same k-order).
// ---------------------------------------------------------------------------
__global__ __launch_bounds__(512, 2) void qk_exp8(
    const u16* __restrict__ q, const u16* __restrict__ k,
    u16* __restrict__ S, float* __restrict__ lsum)
{
  __shared__ u16 lds[65536];                   // 128 KiB

  const int tid = threadIdx.x;
  const int w  = tid >> 6, l = tid & 63;
  const int lr = l & 15, lq = l >> 4;
  const int wA = (w & 1) * 16;                 // A (key) strip
  const int wB = (w >> 1) * 16;                // B (qrow) strip
  const int kb0 = blockIdx.x * 256;            // key base
  const int qb0 = blockIdx.y * 256;            // qrow base
  const int b   = blockIdx.z;
  const size_t rb = (size_t)b * 4096;
  const u16* kg = k + rb * 512;
  const u16* qg = q + rb * 512;

  floatx4 acc[8][4];
  const floatx4 fz = {0.f, 0.f, 0.f, 0.f};
#pragma unroll
  for (int i = 0; i < 8; ++i)
#pragma unroll
    for (int j = 0; j < 4; ++j) acc[i][j] = fz;

  // stage half-tile s: kind 0=A-h0, 1=B-h0, 2=A-h1, 3=B-h1 of tile s>>2
  auto stage = [&](int s) {
    const int ts = s >> 2, kind = s & 3;
    const int mat = kind & 1, h = kind >> 1;   // mat: 0=A(k) 1=B(q)
    const u16* src = mat ? qg : kg;
    const int rbase = mat ? qb0 : kb0;
    u16* dst = &lds[(ts & 1) * 32768 + mat * 16384];
#pragma unroll
    for (int i = 0; i < 2; ++i) {
      const int c = i * 512 + tid;             // 16B chunk within half
      const int r = h * 128 + (c >> 3), k16 = c & 7;
      const int k16s = k16 ^ (r & 7);          // inverse-swizzled source
      GLD_LDS16(src + (size_t)(rbase + r) * 512 + ts * 64 + k16s * 8,
                &dst[r * 64 + k16 * 8]);
    }
  };

  // prologue: 6 half-tiles (tile0 complete + A0,B0 of tile1)
#pragma unroll
  for (int s = 0; s < 6; ++s) stage(s);
  VMW(4);                                      // tile0 resident
  __builtin_amdgcn_s_barrier();
  __builtin_amdgcn_sched_barrier(0);

  bf16x8 af[4][2];                             // current A-half (persists)
  bf16x8 bf0[2][2], bf1[2][2];                 // B-half0 / B-half1 (persist)

#pragma unroll
  for (int t = 0; t < 8; ++t) {
#pragma unroll
    for (int qd = 0; qd < 4; ++qd) {
      const int fmh = qd >> 1;
      const int fnh = fmh ^ (qd & 1);          // Gray: 00,01,11,10
      const u16* AB = &lds[(t & 1) * 32768];
      const u16* BB = AB + 16384;

      // ---- ds-reads: only what changes this phase ----
      if (qd == 0 || qd == 2) {                // new A-half (8 reads)
#pragma unroll
        for (int im = 0; im < 4; ++im) {
          const int rA = (fmh * 4 + im) * 32 + wA + lr;
#pragma unroll
          for (int ks = 0; ks < 2; ++ks) {
            const int k16p = (ks * 4 + lq) ^ (rA & 7);
            af[im][ks] = *(const bf16x8*)&AB[rA * 64 + k16p * 8];
          }
        }
      }
      if (qd == 0) {                           // B-half0 (4 reads)
#pragma unroll
        for (int jn = 0; jn < 2; ++jn) {
          const int rB = jn * 64 + wB + lr;
#pragma unroll
          for (int ks = 0; ks < 2; ++ks) {
            const int k16p = (ks * 4 + lq) ^ (rB & 7);
            bf0[jn][ks] = *(const bf16x8*)&BB[rB * 64 + k16p * 8];
          }
        }
      }
      if (qd == 1) {                           // B-half1 (4 reads)
#pragma unroll
        for (int jn = 0; jn < 2; ++jn) {
          const int rB = (2 + jn) * 64 + wB + lr;
#pragma unroll
          for (int ks = 0; ks < 2; ++ks) {
            const int k16p = (ks * 4 + lq) ^ (rB & 7);
            bf1[jn][ks] = *(const bf16x8*)&BB[rB * 64 + k16p * 8];
          }
        }
      }

      // ---- stage one half-tile (2 x global_load_lds) ----
      const int s = t * 4 + qd + 6;
      if (s < 32) stage(s);

      __builtin_amdgcn_sched_barrier(0);
      __builtin_amdgcn_s_barrier();
      asm volatile("s_waitcnt lgkmcnt(0)" ::: "memory");
      __builtin_amdgcn_sched_barrier(0);        // rule #18: pin MFMA after wait

      __builtin_amdgcn_s_setprio(1);
      if (fnh) {
#pragma unroll
        for (int im = 0; im < 4; ++im)
#pragma unroll
          for (int jn = 0; jn < 2; ++jn)
#pragma unroll
            for (int ks = 0; ks < 2; ++ks)
              acc[fmh * 4 + im][2 + jn] =
                  __builtin_amdgcn_mfma_f32_16x16x32_bf16(
                      af[im][ks], bf1[jn][ks], acc[fmh * 4 + im][2 + jn], 0, 0, 0);
      } else {
#pragma unroll
        for (int im = 0; im < 4; ++im)
#pragma unroll
          for (int jn = 0; jn < 2; ++jn)
#pragma unroll
            for (int ks = 0; ks < 2; ++ks)
              acc[fmh * 4 + im][jn] =
                  __builtin_amdgcn_mfma_f32_16x16x32_bf16(
                      af[im][ks], bf0[jn][ks], acc[fmh * 4 + im][jn], 0, 0, 0);
      }
      __builtin_amdgcn_s_setprio(0);

      if (qd == 3) {
        if (t < 6)        VMW(4);
        else if (t == 6)  VMW(0);
      }
      __builtin_amdgcn_s_barrier();
      __builtin_amdgcn_sched_barrier(0);
    }
  }

  // ---- epilogue: exp2, packed 8B P stores, per-qrow sum atomics ----
  const int cr = lq * 4;
  u16* Sb = S + ((size_t)b << 24);             // b * 4096 * 4096
  float js[4] = {0.f, 0.f, 0.f, 0.f};
#pragma unroll
  for (int fm = 0; fm < 8; ++fm)
#pragma unroll
    for (int fn = 0; fn < 4; ++fn) {
      const int key = kb0 + fm * 32 + wA + cr;
      const int qr  = qb0 + fn * 64 + wB + lr;
      ushortx4 pk;
      float s4 = 0.f;
#pragma unroll
      for (int r = 0; r < 4; ++r) {
        const float p = __builtin_amdgcn_exp2f(acc[fm][fn][r] - 17.31234049f);
        s4 += p;
        pk[r] = f2bf(p);
      }
      js[fn] += s4;
      *(ushortx4*)&Sb[(size_t)qr * 4096 + key] = pk;
    }
#pragma unroll
  for (int fn = 0; fn < 4; ++fn) {
    float s = js[fn];
    s += __shfl_xor(s, 16);                    // reduce over key-quads (lq)
    s += __shfl_xor(s, 32);
    if (lq == 0)
      atomicAdd(&lsum[rb + qb0 + fn * 64 + wB + lr], s);
  }
}

// ---------------------------------------------------------------------------
// Kernel 3 (REWRITTEN this round): pv8 — 8-phase schedule at its ideal
// regime: K=4096 (64 K-tiles).  BM=256 (merged b*S rows; 4096%256==0 keeps
// tiles batch-pure), BN=128 -> grid 256 blocks (full machine; 256^2 would
// give only 128).  8 waves = 2M x 4N, per-wave 128x32, 2 phases/K-tile,
// 16 MFMA + {12,8} ds_read_b128 per phase, B read once per K-tile.
// LDS: 2 x (A 256x64 + B 128x64) bf16 = 96 KiB, st-swizzled both sides.
// Stage stream (3 x 16KB chunks/tile: A0,A1,B): A1(t+1) issued at p0,
// A0/B(t+2) at p1 (never same-phase as a reader of that region; 1 full
// barrier + lgkmcnt(0) separation everywhere).  Counted vmcnt(4) once per
// tile keeps the 2 newest chunks in flight and proves tile t+1 resident.
// XCD-chunked bijective swizzle (256%8==0), n-fastest: the 4 d-siblings of
// each P-panel stay chunk-adjacent (keeps round-1's verified L2 win).
// ---------------------------------------------------------------------------
#define PV_STG_A(TT, CK) do {                                                  \
    u16* dA_ = &lds[((TT) & 1) * 24576];                                       \
    _Pragma("unroll")                                                          \
    for (int i_ = 0; i_ < 2; ++i_) {                                           \
      const int c_ = i_ * 512 + tid, r_ = c_ >> 3, k_ = c_ & 7;                \
      GLD_LDS16(Sb + (size_t)(lm0 + (CK) * 128 + r_) * 4096 + (TT) * 64 +      \
                    (k_ ^ (r_ & 7)) * 8,                                       \
                &dA_[((CK) * 128 + r_) * 64 + k_ * 8]);                        \
    }                                                                          \
  } while (0)

#define PV_STG_B(TT) do {                                                      \
    u16* dB_ = &lds[((TT) & 1) * 24576 + 16384];                               \
    _Pragma("unroll")                                                          \
    for (int i_ = 0; i_ < 2; ++i_) {                                           \
      const int c_ = i_ * 512 + tid, r_ = c_ >> 3, k_ = c_ & 7;                \
      GLD_LDS16(vt + (size_t)(n0 + r_) * 16384 + bofs + (TT) * 64 +            \
                    (k_ ^ (r_ & 7)) * 8,                                       \
                &dB_[r_ * 64 + k_ * 8]);                                       \
    }                                                                          \
  } while (0)

#define PV_PH(T, PH, STAGE_CODE, TAIL_CODE) do {                               \
    const u16* AB_ = &lds[((T) & 1) * 24576];                                  \
    const u16* BB_ = AB_ + 16384;                                              \
    _Pragma("unroll")                                                          \
    for (int im_ = 0; im_ < 4; ++im_) {                                        \
      const int rA_ = ((PH) * 4 + im_) * 32 + wm16 + lr;                       \
      _Pragma("unroll")                                                        \
      for (int ks_ = 0; ks_ < 2; ++ks_) {                                      \
        const int kp_ = (ks_ * 4 + lq) ^ (rA_ & 7);                            \
        af[im_][ks_] = *(const bf16x8*)&AB_[rA_ * 64 + kp_ * 8];               \
      }                                                                        \
    }                                                                          \
    if ((PH) == 0) {                                                           \
      _Pragma("unroll")                                                        \
      for (int jn_ = 0; jn_ < 2; ++jn_) {                                      \
        const int rB_ = wn32 + jn_ * 16 + lr;                                  \
        _Pragma("unroll")                                                      \
        for (int ks_ = 0; ks_ < 2; ++ks_) {                                    \
          const int kp_ = (ks_ * 4 + lq) ^ (rB_ & 7);                          \
          bfv[jn_][ks_] = *(const bf16x8*)&BB_[rB_ * 64 + kp_ * 8];            \
        }                                                                      \
      }                                                                        \
    }                                                                          \
    STAGE_CODE;                                                                \
    __builtin_amdgcn_sched_barrier(0);                                         \
    __builtin_amdgcn_s_barrier();                                              \
    asm volatile("s_waitcnt lgkmcnt(0)" ::: "memory");                         \
    __builtin_amdgcn_sched_barrier(0);                                         \
    __builtin_amdgcn_s_setprio(1);                                             \
    _Pragma("unroll")                                                          \
    for (int im_ = 0; im_ < 4; ++im_)                                          \
      _Pragma("unroll")                                                        \
      for (int jn_ = 0; jn_ < 2; ++jn_)                                        \
        _Pragma("unroll")                                                      \
        for (int ks_ = 0; ks_ < 2; ++ks_)                                      \
          acc[(PH) * 4 + im_][jn_] = __builtin_amdgcn_mfma_f32_16x16x32_bf16(  \
              af[im_][ks_], bfv[jn_][ks_], acc[(PH) * 4 + im_][jn_], 0, 0, 0); \
    __builtin_amdgcn_s_setprio(0);                                             \
    TAIL_CODE;                                                                 \
    __builtin_amdgcn_s_barrier();                                              \
    __builtin_amdgcn_sched_barrier(0);                                         \
  } while (0)

#define PV_TILE(T, G_A1, G_A0B, VMCODE) do {                                   \
    PV_PH(T, 0, { if (G_A1) PV_STG_A((T) + 1, 1); }, (void)0);                 \
    PV_PH(T, 1, { if (G_A0B) { PV_STG_A((T) + 2, 0); PV_STG_B((T) + 2); } },   \
          VMCODE);                                                             \
  } while (0)

__global__ __launch_bounds__(512, 2) void pv8(
    const u16* __restrict__ S, const u16* __restrict__ vt,
    const float* __restrict__ lsum, float* __restrict__ out)
{
  __shared__ u16 lds[49152];                   // 96 KiB

  const int tid = threadIdx.x;
  const int w  = tid >> 6, l = tid & 63;
  const int lr = l & 15, lq = l >> 4;
  const int wm16 = (w & 1) * 16;               // M strip within 32-row fm blk
  const int wn32 = (w >> 1) * 32;              // N strip (32 cols)

  const int wg = blockIdx.x;                   // 0..255
  const int li = (wg & 7) * 32 + (wg >> 3);    // bijective XCD-chunked
  const int n0 = (li & 3) * 128;               // d base
  const int m0 = (li >> 2) * 256;              // merged q-row base
  const int b  = m0 >> 12;
  const int lm0 = m0 & 4095;
  const u16* Sb = S + ((size_t)b << 24);
  const size_t bofs = (size_t)b * 4096;

  floatx4 acc[8][2];
  const floatx4 fz = {0.f, 0.f, 0.f, 0.f};
#pragma unroll
  for (int i = 0; i < 8; ++i) { acc[i][0] = fz; acc[i][1] = fz; }

  bf16x8 af[4][2], bfv[2][2];

  // prologue: tile0 (A0,B,A1) + A0,B of tile1; vmcnt(4) leaves the newest
  // 2 chunks (tile1's A0,B) in flight -> tile0 resident.
  PV_STG_A(0, 0); PV_STG_B(0); PV_STG_A(0, 1); PV_STG_A(1, 0); PV_STG_B(1);
  VMW(4);
  __builtin_amdgcn_s_barrier();
  __builtin_amdgcn_sched_barrier(0);

  for (int t = 0; t < 62; t += 2) {
    PV_TILE(t,     1, 1, VMW(4));
    PV_TILE(t + 1, 1, 1, VMW(4));
  }
  PV_TILE(62, 1, 0, VMW(0));                   // stages A1(63); drain all
  PV_TILE(63, 0, 0, (void)0);

  // ---- epilogue: scale by 1/lsum, store fp32 ----
  const int cr = lq * 4;
#pragma unroll
  for (int fm = 0; fm < 8; ++fm) {
    const int m = m0 + fm * 32 + wm16 + cr;    // global merged q-row
    float inv[4];
#pragma unroll
    for (int r = 0; r < 4; ++r) inv[r] = 1.0f / lsum[m + r];
#pragma unroll
    for (int jn = 0; jn < 2; ++jn) {
      const int n = n0 + wn32 + jn * 16 + lr;
#pragma unroll
      for (int r = 0; r < 4; ++r)
        out[(size_t)(m + r) * 512 + n] = acc[fm][jn][r] * inv[r];
    }
  }
}

// ---------------------------------------------------------------------------
extern "C" void kernel_launch(void* const* d_in, const int* in_sizes, int n_in,
                              void* d_out, int out_size, void* d_ws, size_t ws_size,
                              hipStream_t stream) {
  (void)in_sizes; (void)n_in; (void)out_size; (void)ws_size;
  const float* x  = (const float*)d_in[0];
  const float* Wq = (const float*)d_in[1];
  const float* Wk = (const float*)d_in[2];
  const float* Wv = (const float*)d_in[3];
  float* out = (float*)d_out;
  u16* ws  = (u16*)d_ws;
  u16* qw  = ws;                                  // q row-major, 16 MB
  u16* kw  = qw + (size_t)16384 * 512;            // k row-major, 16 MB
  u16* vw  = kw + (size_t)16384 * 512;            // v^T [512][16384], 16 MB
  u16* x16 = vw + (size_t)16384 * 512;            // x bf16, 16 MB
  u16* wb  = x16 + (size_t)16384 * 512;           // weights bf16, 1.5 MB
  u16* Sp  = wb + (size_t)3 * 262144;             // P bf16 [4][4096][4096], 128 MB
  float* lsum = (float*)(Sp + ((size_t)4 << 24)); // [16384] fp32, 64 KB

  hipMemsetAsync(lsum, 0, 16384 * sizeof(float), stream);
  cvt_w<<<dim3(128, 3), dim3(256), 0, stream>>>(Wq, Wk, Wv, wb);
  cvt_x<<<dim3(4096), dim3(256), 0, stream>>>(x, x16);
  qkv_gemm<<<dim3(128, 4, 3), dim3(256), 0, stream>>>(x16, wb, qw, kw, vw);
  qk_exp8<<<dim3(16, 16, 4), dim3(512), 0, stream>>>(qw, kw, Sp, lsum);
  pv8<<<dim3(256), dim3(512), 0, stream>>>(Sp, vw, lsum, out);
}

// Round 5
// 279.622 us; speedup vs baseline: 1.1423x; 1.0405x over previous
//
#include <hip/hip_runtime.h>
#include <stdint.h>

typedef unsigned short u16;
typedef __bf16  bf16x8   __attribute__((ext_vector_type(8)));
typedef float   floatx4  __attribute__((ext_vector_type(4)));
typedef unsigned short ushortx4 __attribute__((ext_vector_type(4)));

__device__ __forceinline__ u16 f2bf(float f) {
  unsigned u = __builtin_bit_cast(unsigned, f);
  u += 0x7FFFu + ((u >> 16) & 1u);           // RNE; inputs are finite
  return (u16)(u >> 16);
}

#define GLD_LDS16(g, l)                                                        \
  __builtin_amdgcn_global_load_lds(                                            \
      (const __attribute__((address_space(1))) void*)(g),                      \
      (__attribute__((address_space(3))) void*)(l), 16, 0, 0)

#define VMW(N) asm volatile("s_waitcnt vmcnt(" #N ")" ::: "memory")

// ---------------------------------------------------------------------------
// Kernel 0a: weights fp32 -> bf16 (unchanged; verified).
// ---------------------------------------------------------------------------
__global__ __launch_bounds__(256) void cvt_w(
    const float* __restrict__ Wq, const float* __restrict__ Wk,
    const float* __restrict__ Wv, u16* __restrict__ dst)
{
  const int z = blockIdx.y;
  const float* src = (z == 0) ? Wq : (z == 1) ? Wk : Wv;
  u16* d = dst + (size_t)z * 262144;
  const int idx = (blockIdx.x * 256 + threadIdx.x) * 8;
  const float4 lo = *(const float4*)&src[idx];
  const float4 hi = *(const float4*)&src[idx + 4];
  union { u16 h[8]; uint4 v; } pk;
  pk.h[0] = f2bf(lo.x); pk.h[1] = f2bf(lo.y); pk.h[2] = f2bf(lo.z); pk.h[3] = f2bf(lo.w);
  pk.h[4] = f2bf(hi.x); pk.h[5] = f2bf(hi.y); pk.h[6] = f2bf(hi.z); pk.h[7] = f2bf(hi.w);
  *(uint4*)&d[idx] = pk.v;
}

// ---------------------------------------------------------------------------
// Kernel 0b: x fp32 -> bf16 (unchanged; verified).
// ---------------------------------------------------------------------------
__global__ __launch_bounds__(256) void cvt_x(
    const float* __restrict__ X, u16* __restrict__ dst)
{
  const int idx = (blockIdx.x * 256 + threadIdx.x) * 8;
  const float4 lo = *(const float4*)&X[idx];
  const float4 hi = *(const float4*)&X[idx + 4];
  union { u16 h[8]; uint4 v; } pk;
  pk.h[0] = f2bf(lo.x); pk.h[1] = f2bf(lo.y); pk.h[2] = f2bf(lo.z); pk.h[3] = f2bf(lo.w);
  pk.h[4] = f2bf(hi.x); pk.h[5] = f2bf(hi.y); pk.h[6] = f2bf(hi.z); pk.h[7] = f2bf(hi.w);
  *(uint4*)&dst[idx] = pk.v;
}

// ---------------------------------------------------------------------------
// Kernel 1: qkv8 — fused QKV projection on the 8-phase 256^2 skeleton
// (verbatim clone of qk_exp8's twice-verified main loop: same stage stream,
// Gray-code quadrants, persistent operand regs, vmcnt(4)/vmcnt(0) schedule).
// Per-z operand roles chosen so EVERY epilogue store is a packed 8B
// ushortx4:
//   z=0: A=Wq (M=d),  B=X (N=bs) -> q[bs][d], 4 consecutive d per thread
//   z=1: A=Wk (M=d),  B=X (N=bs) -> k[bs][d]
//   z=2: A=X  (M=bs), B=Wv (N=d) -> vt[d][bs], 4 consecutive bs per thread
// Unified epilogue: dst[n_outer*ostr + m_inner4] (layouts identical to the
// round-0-verified q/k/vt epilogues; C = A·B^T convention verified r0-r3).
// Grid: 384 blocks (z<2: 2 m-blk x 64 n-blk; z=2: 64 x 2), bijective
// 8x48 XCD chunking.  K=512 -> 8 K-tiles, 32 phases, 1.5 machine-rounds
// (vs 6 rounds of the old 128^2 m97 kernel).
// [Round 4: unchanged resubmit — round-4 bench was an infra failure
//  ("container failed twice"); audit found uniform barriers, in-range
//  addresses, graph-capture-safe launches.]
// ---------------------------------------------------------------------------
__global__ __launch_bounds__(512, 2) void qkv8(
    const u16* __restrict__ X16, const u16* __restrict__ Wb,
    u16* __restrict__ qo, u16* __restrict__ ko, u16* __restrict__ vto)
{
  __shared__ u16 lds[65536];                   // 128 KiB

  const int tid = threadIdx.x;
  const int w  = tid >> 6, l = tid & 63;
  const int lr = l & 15, lq = l >> 4;
  const int wA = (w & 1) * 16;                 // A(M) strip
  const int wB = (w >> 1) * 16;                // B(N) strip

  const int bx = blockIdx.x;                   // 0..383
  const int li = (bx & 7) * 48 + (bx >> 3);    // bijective XCD chunking
  const int z  = li >> 7, u = li & 127;        // 384 = 3*128

  const u16* Ag; const u16* Bg; u16* dst; float sc; size_t ostr; int mb, nb;
  if (z < 2) {
    Ag = Wb + (size_t)z * 262144; Bg = X16;
    dst = z ? ko : qo; sc = z ? 1.0f : 0.06375871732f; ostr = 512;
    mb = (u & 1) * 256;  nb = (u >> 1) * 256;  // M over 512 d, N over 16384 bs
  } else {
    Ag = X16; Bg = Wb + (size_t)2 * 262144;
    dst = vto; sc = 1.0f; ostr = 16384;
    mb = (u >> 1) * 256; nb = (u & 1) * 256;   // M over 16384 bs, N over 512 d
  }

  floatx4 acc[8][4];
  const floatx4 fz = {0.f, 0.f, 0.f, 0.f};
#pragma unroll
  for (int i = 0; i < 8; ++i)
#pragma unroll
    for (int j = 0; j < 4; ++j) acc[i][j] = fz;

  // stage half-tile s: kind 0=A-h0, 1=B-h0, 2=A-h1, 3=B-h1 of tile s>>2
  auto stage = [&](int s) {
    const int ts = s >> 2, kind = s & 3;
    const int mat = kind & 1, h = kind >> 1;
    const u16* src = mat ? Bg : Ag;
    const int rbase = mat ? nb : mb;
    u16* dstl = &lds[(ts & 1) * 32768 + mat * 16384];
#pragma unroll
    for (int i = 0; i < 2; ++i) {
      const int c = i * 512 + tid;             // 16B chunk within half
      const int r = h * 128 + (c >> 3), k16 = c & 7;
      const int k16s = k16 ^ (r & 7);          // inverse-swizzled source
      GLD_LDS16(src + (size_t)(rbase + r) * 512 + ts * 64 + k16s * 8,
                &dstl[r * 64 + k16 * 8]);
    }
  };

  // prologue: 6 half-tiles (tile0 complete + A0,B0 of tile1)
#pragma unroll
  for (int s = 0; s < 6; ++s) stage(s);
  VMW(4);                                      // tile0 resident
  __builtin_amdgcn_s_barrier();
  __builtin_amdgcn_sched_barrier(0);

  bf16x8 af[4][2];                             // current A-half (persists)
  bf16x8 bf0[2][2], bf1[2][2];                 // B-half0 / B-half1 (persist)

#pragma unroll
  for (int t = 0; t < 8; ++t) {
#pragma unroll
    for (int qd = 0; qd < 4; ++qd) {
      const int fmh = qd >> 1;
      const int fnh = fmh ^ (qd & 1);          // Gray: 00,01,11,10
      const u16* AB = &lds[(t & 1) * 32768];
      const u16* BB = AB + 16384;

      if (qd == 0 || qd == 2) {                // new A-half (8 reads)
#pragma unroll
        for (int im = 0; im < 4; ++im) {
          const int rA = (fmh * 4 + im) * 32 + wA + lr;
#pragma unroll
          for (int ks = 0; ks < 2; ++ks) {
            const int k16p = (ks * 4 + lq) ^ (rA & 7);
            af[im][ks] = *(const bf16x8*)&AB[rA * 64 + k16p * 8];
          }
        }
      }
      if (qd == 0) {                           // B-half0 (4 reads)
#pragma unroll
        for (int jn = 0; jn < 2; ++jn) {
          const int rB = jn * 64 + wB + lr;
#pragma unroll
          for (int ks = 0; ks < 2; ++ks) {
            const int k16p = (ks * 4 + lq) ^ (rB & 7);
            bf0[jn][ks] = *(const bf16x8*)&BB[rB * 64 + k16p * 8];
          }
        }
      }
      if (qd == 1) {                           // B-half1 (4 reads)
#pragma unroll
        for (int jn = 0; jn < 2; ++jn) {
          const int rB = (2 + jn) * 64 + wB + lr;
#pragma unroll
          for (int ks = 0; ks < 2; ++ks) {
            const int k16p = (ks * 4 + lq) ^ (rB & 7);
            bf1[jn][ks] = *(const bf16x8*)&BB[rB * 64 + k16p * 8];
          }
        }
      }

      const int s = t * 4 + qd + 6;
      if (s < 32) stage(s);

      __builtin_amdgcn_sched_barrier(0);
      __builtin_amdgcn_s_barrier();
      asm volatile("s_waitcnt lgkmcnt(0)" ::: "memory");
      __builtin_amdgcn_sched_barrier(0);        // rule #18: pin MFMA after wait

      __builtin_amdgcn_s_setprio(1);
      if (fnh) {
#pragma unroll
        for (int im = 0; im < 4; ++im)
#pragma unroll
          for (int jn = 0; jn < 2; ++jn)
#pragma unroll
            for (int ks = 0; ks < 2; ++ks)
              acc[fmh * 4 + im][2 + jn] =
                  __builtin_amdgcn_mfma_f32_16x16x32_bf16(
                      af[im][ks], bf1[jn][ks], acc[fmh * 4 + im][2 + jn], 0, 0, 0);
      } else {
#pragma unroll
        for (int im = 0; im < 4; ++im)
#pragma unroll
          for (int jn = 0; jn < 2; ++jn)
#pragma unroll
            for (int ks = 0; ks < 2; ++ks)
              acc[fmh * 4 + im][jn] =
                  __builtin_amdgcn_mfma_f32_16x16x32_bf16(
                      af[im][ks], bf0[jn][ks], acc[fmh * 4 + im][jn], 0, 0, 0);
      }
      __builtin_amdgcn_s_setprio(0);

      if (qd == 3) {
        if (t < 6)        VMW(4);
        else if (t == 6)  VMW(0);
      }
      __builtin_amdgcn_s_barrier();
      __builtin_amdgcn_sched_barrier(0);
    }
  }

  // ---- epilogue: 32 packed 8B stores, unified across z ----
  // acc[fm][fn]: m (A-row) = mb + fm*32 + wA + lq*4 + r  (4 consecutive),
  //              n (B-row) = nb + fn*64 + wB + lr.
  const int cr = lq * 4;
#pragma unroll
  for (int fm = 0; fm < 8; ++fm)
#pragma unroll
    for (int fn = 0; fn < 4; ++fn) {
      const int mv = mb + fm * 32 + wA + cr;
      const int nv = nb + fn * 64 + wB + lr;
      ushortx4 pk;
#pragma unroll
      for (int r = 0; r < 4; ++r) pk[r] = f2bf(acc[fm][fn][r] * sc);
      *(ushortx4*)&dst[(size_t)nv * ostr + mv] = pk;
    }
}

// ---------------------------------------------------------------------------
// Kernel 2: 8-phase 256^2 qk_exp8 (unchanged — round-3 control, ~99 us).
// ---------------------------------------------------------------------------
__global__ __launch_bounds__(512, 2) void qk_exp8(
    const u16* __restrict__ q, const u16* __restrict__ k,
    u16* __restrict__ S, float* __restrict__ lsum)
{
  __shared__ u16 lds[65536];                   // 128 KiB

  const int tid = threadIdx.x;
  const int w  = tid >> 6, l = tid & 63;
  const int lr = l & 15, lq = l >> 4;
  const int wA = (w & 1) * 16;                 // A (key) strip
  const int wB = (w >> 1) * 16;                // B (qrow) strip
  const int kb0 = blockIdx.x * 256;            // key base
  const int qb0 = blockIdx.y * 256;            // qrow base
  const int b   = blockIdx.z;
  const size_t rb = (size_t)b * 4096;
  const u16* kg = k + rb * 512;
  const u16* qg = q + rb * 512;

  floatx4 acc[8][4];
  const floatx4 fz = {0.f, 0.f, 0.f, 0.f};
#pragma unroll
  for (int i = 0; i < 8; ++i)
#pragma unroll
    for (int j = 0; j < 4; ++j) acc[i][j] = fz;

  auto stage = [&](int s) {
    const int ts = s >> 2, kind = s & 3;
    const int mat = kind & 1, h = kind >> 1;   // mat: 0=A(k) 1=B(q)
    const u16* src = mat ? qg : kg;
    const int rbase = mat ? qb0 : kb0;
    u16* dst = &lds[(ts & 1) * 32768 + mat * 16384];
#pragma unroll
    for (int i = 0; i < 2; ++i) {
      const int c = i * 512 + tid;             // 16B chunk within half
      const int r = h * 128 + (c >> 3), k16 = c & 7;
      const int k16s = k16 ^ (r & 7);          // inverse-swizzled source
      GLD_LDS16(src + (size_t)(rbase + r) * 512 + ts * 64 + k16s * 8,
                &dst[r * 64 + k16 * 8]);
    }
  };

#pragma unroll
  for (int s = 0; s < 6; ++s) stage(s);
  VMW(4);                                      // tile0 resident
  __builtin_amdgcn_s_barrier();
  __builtin_amdgcn_sched_barrier(0);

  bf16x8 af[4][2];                             // current A-half (persists)
  bf16x8 bf0[2][2], bf1[2][2];                 // B-half0 / B-half1 (persist)

#pragma unroll
  for (int t = 0; t < 8; ++t) {
#pragma unroll
    for (int qd = 0; qd < 4; ++qd) {
      const int fmh = qd >> 1;
      const int fnh = fmh ^ (qd & 1);          // Gray: 00,01,11,10
      const u16* AB = &lds[(t & 1) * 32768];
      const u16* BB = AB + 16384;

      if (qd == 0 || qd == 2) {                // new A-half (8 reads)
#pragma unroll
        for (int im = 0; im < 4; ++im) {
          const int rA = (fmh * 4 + im) * 32 + wA + lr;
#pragma unroll
          for (int ks = 0; ks < 2; ++ks) {
            const int k16p = (ks * 4 + lq) ^ (rA & 7);
            af[im][ks] = *(const bf16x8*)&AB[rA * 64 + k16p * 8];
          }
        }
      }
      if (qd == 0) {                           // B-half0 (4 reads)
#pragma unroll
        for (int jn = 0; jn < 2; ++jn) {
          const int rB = jn * 64 + wB + lr;
#pragma unroll
          for (int ks = 0; ks < 2; ++ks) {
            const int k16p = (ks * 4 + lq) ^ (rB & 7);
            bf0[jn][ks] = *(const bf16x8*)&BB[rB * 64 + k16p * 8];
          }
        }
      }
      if (qd == 1) {                           // B-half1 (4 reads)
#pragma unroll
        for (int jn = 0; jn < 2; ++jn) {
          const int rB = (2 + jn) * 64 + wB + lr;
#pragma unroll
          for (int ks = 0; ks < 2; ++ks) {
            const int k16p = (ks * 4 + lq) ^ (rB & 7);
            bf1[jn][ks] = *(const bf16x8*)&BB[rB * 64 + k16p * 8];
          }
        }
      }

      const int s = t * 4 + qd + 6;
      if (s < 32) stage(s);

      __builtin_amdgcn_sched_barrier(0);
      __builtin_amdgcn_s_barrier();
      asm volatile("s_waitcnt lgkmcnt(0)" ::: "memory");
      __builtin_amdgcn_sched_barrier(0);        // rule #18: pin MFMA after wait

      __builtin_amdgcn_s_setprio(1);
      if (fnh) {
#pragma unroll
        for (int im = 0; im < 4; ++im)
#pragma unroll
          for (int jn = 0; jn < 2; ++jn)
#pragma unroll
            for (int ks = 0; ks < 2; ++ks)
              acc[fmh * 4 + im][2 + jn] =
                  __builtin_amdgcn_mfma_f32_16x16x32_bf16(
                      af[im][ks], bf1[jn][ks], acc[fmh * 4 + im][2 + jn], 0, 0, 0);
      } else {
#pragma unroll
        for (int im = 0; im < 4; ++im)
#pragma unroll
          for (int jn = 0; jn < 2; ++jn)
#pragma unroll
            for (int ks = 0; ks < 2; ++ks)
              acc[fmh * 4 + im][jn] =
                  __builtin_amdgcn_mfma_f32_16x16x32_bf16(
                      af[im][ks], bf0[jn][ks], acc[fmh * 4 + im][jn], 0, 0, 0);
      }
      __builtin_amdgcn_s_setprio(0);

      if (qd == 3) {
        if (t < 6)        VMW(4);
        else if (t == 6)  VMW(0);
      }
      __builtin_amdgcn_s_barrier();
      __builtin_amdgcn_sched_barrier(0);
    }
  }

  const int cr = lq * 4;
  u16* Sb = S + ((size_t)b << 24);             // b * 4096 * 4096
  float js[4] = {0.f, 0.f, 0.f, 0.f};
#pragma unroll
  for (int fm = 0; fm < 8; ++fm)
#pragma unroll
    for (int fn = 0; fn < 4; ++fn) {
      const int key = kb0 + fm * 32 + wA + cr;
      const int qr  = qb0 + fn * 64 + wB + lr;
      ushortx4 pk;
      float s4 = 0.f;
#pragma unroll
      for (int r = 0; r < 4; ++r) {
        const float p = __builtin_amdgcn_exp2f(acc[fm][fn][r] - 17.31234049f);
        s4 += p;
        pk[r] = f2bf(p);
      }
      js[fn] += s4;
      *(ushortx4*)&Sb[(size_t)qr * 4096 + key] = pk;
    }
#pragma unroll
  for (int fn = 0; fn < 4; ++fn) {
    float s = js[fn];
    s += __shfl_xor(s, 16);                    // reduce over key-quads (lq)
    s += __shfl_xor(s, 32);
    if (lq == 0)
      atomicAdd(&lsum[rb + qb0 + fn * 64 + wB + lr], s);
  }
}

// ---------------------------------------------------------------------------
// Kernel 3: pv8 — 8-phase, BM=256/BN=128, K=4096 (unchanged — round-3
// control, ~72 us).
// ---------------------------------------------------------------------------
#define PV_STG_A(TT, CK) do {                                                  \
    u16* dA_ = &lds[((TT) & 1) * 24576];                                       \
    _Pragma("unroll")                                                          \
    for (int i_ = 0; i_ < 2; ++i_) {                                           \
      const int c_ = i_ * 512 + tid, r_ = c_ >> 3, k_ = c_ & 7;                \
      GLD_LDS16(Sb + (size_t)(lm0 + (CK) * 128 + r_) * 4096 + (TT) * 64 +      \
                    (k_ ^ (r_ & 7)) * 8,                                       \
                &dA_[((CK) * 128 + r_) * 64 + k_ * 8]);                        \
    }                                                                          \
  } while (0)

#define PV_STG_B(TT) do {                                                      \
    u16* dB_ = &lds[((TT) & 1) * 24576 + 16384];                               \
    _Pragma("unroll")                                                          \
    for (int i_ = 0; i_ < 2; ++i_) {                                           \
      const int c_ = i_ * 512 + tid, r_ = c_ >> 3, k_ = c_ & 7;                \
      GLD_LDS16(vt + (size_t)(n0 + r_) * 16384 + bofs + (TT) * 64 +            \
                    (k_ ^ (r_ & 7)) * 8,                                       \
                &dB_[r_ * 64 + k_ * 8]);                                       \
    }                                                                          \
  } while (0)

#define PV_PH(T, PH, STAGE_CODE, TAIL_CODE) do {                               \
    const u16* AB_ = &lds[((T) & 1) * 24576];                                  \
    const u16* BB_ = AB_ + 16384;                                              \
    _Pragma("unroll")                                                          \
    for (int im_ = 0; im_ < 4; ++im_) {                                        \
      const int rA_ = ((PH) * 4 + im_) * 32 + wm16 + lr;                       \
      _Pragma("unroll")                                                        \
      for (int ks_ = 0; ks_ < 2; ++ks_) {                                      \
        const int kp_ = (ks_ * 4 + lq) ^ (rA_ & 7);                            \
        af[im_][ks_] = *(const bf16x8*)&AB_[rA_ * 64 + kp_ * 8];               \
      }                                                                        \
    }                                                                          \
    if ((PH) == 0) {                                                           \
      _Pragma("unroll")                                                        \
      for (int jn_ = 0; jn_ < 2; ++jn_) {                                      \
        const int rB_ = wn32 + jn_ * 16 + lr;                                  \
        _Pragma("unroll")                                                      \
        for (int ks_ = 0; ks_ < 2; ++ks_) {                                    \
          const int kp_ = (ks_ * 4 + lq) ^ (rB_ & 7);                          \
          bfv[jn_][ks_] = *(const bf16x8*)&BB_[rB_ * 64 + kp_ * 8];            \
        }                                                                      \
      }                                                                        \
    }                                                                          \
    STAGE_CODE;                                                                \
    __builtin_amdgcn_sched_barrier(0);                                         \
    __builtin_amdgcn_s_barrier();                                              \
    asm volatile("s_waitcnt lgkmcnt(0)" ::: "memory");                         \
    __builtin_amdgcn_sched_barrier(0);                                         \
    __builtin_amdgcn_s_setprio(1);                                             \
    _Pragma("unroll")                                                          \
    for (int im_ = 0; im_ < 4; ++im_)                                          \
      _Pragma("unroll")                                                        \
      for (int jn_ = 0; jn_ < 2; ++jn_)                                        \
        _Pragma("unroll")                                                      \
        for (int ks_ = 0; ks_ < 2; ++ks_)                                      \
          acc[(PH) * 4 + im_][jn_] = __builtin_amdgcn_mfma_f32_16x16x32_bf16(  \
              af[im_][ks_], bfv[jn_][ks_], acc[(PH) * 4 + im_][jn_], 0, 0, 0); \
    __builtin_amdgcn_s_setprio(0);                                             \
    TAIL_CODE;                                                                 \
    __builtin_amdgcn_s_barrier();                                              \
    __builtin_amdgcn_sched_barrier(0);                                         \
  } while (0)

#define PV_TILE(T, G_A1, G_A0B, VMCODE) do {                                   \
    PV_PH(T, 0, { if (G_A1) PV_STG_A((T) + 1, 1); }, (void)0);                 \
    PV_PH(T, 1, { if (G_A0B) { PV_STG_A((T) + 2, 0); PV_STG_B((T) + 2); } },   \
          VMCODE);                                                             \
  } while (0)

__global__ __launch_bounds__(512, 2) void pv8(
    const u16* __restrict__ S, const u16* __restrict__ vt,
    const float* __restrict__ lsum, float* __restrict__ out)
{
  __shared__ u16 lds[49152];                   // 96 KiB

  const int tid = threadIdx.x;
  const int w  = tid >> 6, l = tid & 63;
  const int lr = l & 15, lq = l >> 4;
  const int wm16 = (w & 1) * 16;               // M strip within 32-row fm blk
  const int wn32 = (w >> 1) * 32;              // N strip (32 cols)

  const int wg = blockIdx.x;                   // 0..255
  const int li = (wg & 7) * 32 + (wg >> 3);    // bijective XCD-chunked
  const int n0 = (li & 3) * 128;               // d base
  const int m0 = (li >> 2) * 256;              // merged q-row base
  const int b  = m0 >> 12;
  const int lm0 = m0 & 4095;
  const u16* Sb = S + ((size_t)b << 24);
  const size_t bofs = (size_t)b * 4096;

  floatx4 acc[8][2];
  const floatx4 fz = {0.f, 0.f, 0.f, 0.f};
#pragma unroll
  for (int i = 0; i < 8; ++i) { acc[i][0] = fz; acc[i][1] = fz; }

  bf16x8 af[4][2], bfv[2][2];

  PV_STG_A(0, 0); PV_STG_B(0); PV_STG_A(0, 1); PV_STG_A(1, 0); PV_STG_B(1);
  VMW(4);
  __builtin_amdgcn_s_barrier();
  __builtin_amdgcn_sched_barrier(0);

  for (int t = 0; t < 62; t += 2) {
    PV_TILE(t,     1, 1, VMW(4));
    PV_TILE(t + 1, 1, 1, VMW(4));
  }
  PV_TILE(62, 1, 0, VMW(0));                   // stages A1(63); drain all
  PV_TILE(63, 0, 0, (void)0);

  const int cr = lq * 4;
#pragma unroll
  for (int fm = 0; fm < 8; ++fm) {
    const int m = m0 + fm * 32 + wm16 + cr;    // global merged q-row
    float inv[4];
#pragma unroll
    for (int r = 0; r < 4; ++r) inv[r] = 1.0f / lsum[m + r];
#pragma unroll
    for (int jn = 0; jn < 2; ++jn) {
      const int n = n0 + wn32 + jn * 16 + lr;
#pragma unroll
      for (int r = 0; r < 4; ++r)
        out[(size_t)(m + r) * 512 + n] = acc[fm][jn][r] * inv[r];
    }
  }
}

// ---------------------------------------------------------------------------
extern "C" void kernel_launch(void* const* d_in, const int* in_sizes, int n_in,
                              void* d_out, int out_size, void* d_ws, size_t ws_size,
                              hipStream_t stream) {
  (void)in_sizes; (void)n_in; (void)out_size; (void)ws_size;
  const float* x  = (const float*)d_in[0];
  const float* Wq = (const float*)d_in[1];
  const float* Wk = (const float*)d_in[2];
  const float* Wv = (const float*)d_in[3];
  float* out = (float*)d_out;
  u16* ws  = (u16*)d_ws;
  u16* qw  = ws;                                  // q row-major, 16 MB
  u16* kw  = qw + (size_t)16384 * 512;            // k row-major, 16 MB
  u16* vw  = kw + (size_t)16384 * 512;            // v^T [512][16384], 16 MB
  u16* x16 = vw + (size_t)16384 * 512;            // x bf16, 16 MB
  u16* wb  = x16 + (size_t)16384 * 512;           // weights bf16, 1.5 MB
  u16* Sp  = wb + (size_t)3 * 262144;             // P bf16 [4][4096][4096], 128 MB
  float* lsum = (float*)(Sp + ((size_t)4 << 24)); // [16384] fp32, 64 KB

  hipMemsetAsync(lsum, 0, 16384 * sizeof(float), stream);
  cvt_w<<<dim3(128, 3), dim3(256), 0, stream>>>(Wq, Wk, Wv, wb);
  cvt_x<<<dim3(4096), dim3(256), 0, stream>>>(x, x16);
  qkv8<<<dim3(384), dim3(512), 0, stream>>>(x16, wb, qw, kw, vw);
  qk_exp8<<<dim3(16, 16, 4), dim3(512), 0, stream>>>(qw, kw, Sp, lsum);
  pv8<<<dim3(256), dim3(512), 0, stream>>>(Sp, vw, lsum, out);
}